// Round 6
// baseline (160.481 us; speedup 1.0000x reference)
//
#include <hip/hip_runtime.h>
#include <hip/hip_bf16.h>
#include <math.h>

#define HSZ   1024
#define NHEAD 16
#define HDIM  64
#define BATCH 2
#define SEQ   2048

#define LOG2E 1.4426950408889634f

typedef __attribute__((ext_vector_type(8))) short short8;
typedef __attribute__((ext_vector_type(4))) short short4_t;
typedef __attribute__((ext_vector_type(4))) float floatx4;

typedef __attribute__((address_space(1))) const unsigned int gu32;
typedef __attribute__((address_space(3))) unsigned int lu32;

__device__ __forceinline__ void g2lds16(const void* g, void* l) {
    // async global->LDS DMA, 16B per lane; LDS dest = wave-uniform base + lane*16
    __builtin_amdgcn_global_load_lds((gu32*)g, (lu32*)l, 16, 0, 0);
}

__device__ __forceinline__ short f2bf(float f) {
    union { float f; unsigned u; } v; v.f = f;
    unsigned r = (v.u + 0x7FFF + ((v.u >> 16) & 1)) >> 16;  // RNE
    return (short)r;
}

__device__ __forceinline__ unsigned pk2(float a, float b) {
    __hip_bfloat162 h = __float22bfloat162_rn(make_float2(a, b));
    return *(unsigned*)&h;   // low = a, high = b
}

__device__ __forceinline__ float ex2(float x) {
#if __has_builtin(__builtin_amdgcn_exp2f)
    return __builtin_amdgcn_exp2f(x);
#else
    return exp2f(x);
#endif
}

// ---------------------------------------------------------------------------
// K1: fp32 -> bf16 convert (X, Wq|Wk|Wv concat) + mask prescale by log2e
// ---------------------------------------------------------------------------
__global__ __launch_bounds__(256) void convert_kernel(
    const float4* __restrict__ X, const float4* __restrict__ Wq,
    const float4* __restrict__ Wk, const float4* __restrict__ Wv,
    const float4* __restrict__ Mask,
    short4_t* __restrict__ Xb, short4_t* __restrict__ Wb,
    float4* __restrict__ Mw)
{
    int idx = blockIdx.x * 256 + threadIdx.x;      // 1,836,032 total
    if (idx >= 1835008) {                           // mask: 1024 float4
        int t = idx - 1835008;
        float4 f = Mask[t];
        float4 o;
        o.x = f.x * LOG2E; o.y = f.y * LOG2E;
        o.z = f.z * LOG2E; o.w = f.w * LOG2E;
        Mw[t] = o;
        return;
    }
    const float4* src; short4_t* dst;
    if (idx < 1048576) { src = X + idx; dst = Xb + idx; }
    else {
        int t = idx - 1048576;
        int sel = t >> 18;                          // 262144 float4 per W
        int wi  = t & 0x3FFFF;
        src = (sel == 0 ? Wq : sel == 1 ? Wk : Wv) + wi;
        dst = Wb + (sel << 18) + wi;
    }
    float4 f = *src;
    short4_t o;
    o.x = f2bf(f.x); o.y = f2bf(f.y); o.z = f2bf(f.z); o.w = f2bf(f.w);
    *dst = o;
}

// ---------------------------------------------------------------------------
// K2: QKV projection, bf16 MFMA. C[4096][3072] = Xb[4096][1024] * Wb^T.
// 128x128 tile, BK=64, global_load_lds w=16, XOR-swizzled LDS.
// q -> [B,NH,S,HD] scaled by 0.125*log2e; k -> [B,NH,S,HD];
// v -> TRANSPOSED [B*NH, HD, S] with key order PERMUTED within each
//     64-column group: block-of-4 b=(kh,jh,q) -> kh*8+q*2+jh, so the
//     attention PV A-fragment (packed from the S^T C-layout without any
//     cross-lane moves) contracts against matching V columns.
// ---------------------------------------------------------------------------
__global__ __launch_bounds__(256, 3) void qkv_mfma_kernel(
    const short* __restrict__ Xb, const short* __restrict__ Wb,
    const float* __restrict__ bq, const float* __restrict__ bk,
    const float* __restrict__ bv,
    short* __restrict__ qo, short* __restrict__ ko, short* __restrict__ vT)
{
    __shared__ short Sm[128 * 132];      // A/B staging (16384) + V transpose (16896)
    short* As = Sm;
    short* Bs = Sm + 8192;

    const int tid  = threadIdx.x;
    const int lane = tid & 63;
    const int w    = tid >> 6;
    const int l    = lane & 15, quad = lane >> 4;
    const int gM   = blockIdx.y * 128;
    const int gN   = blockIdx.x * 128;      // 0..3071 across q|k|v
    const int wm   = (w >> 1) * 64, wn = (w & 1) * 64;
    const int ci   = lane >> 3, pb = lane & 7;

    floatx4 acc[4][4] = {};

    for (int kt = 0; kt < HSZ / 64; ++kt) {
        const int k0 = kt * 64;
        __syncthreads();
        #pragma unroll
        for (int u = 0; u < 4; ++u) {
            int c  = w * 4 + u;                 // chunk 0..15 (1KB each)
            int r  = c * 8 + ci;                // tile row
            int lb = pb ^ (r & 7);              // logical 16B block
            g2lds16(Xb + (size_t)(gM + r) * HSZ + k0 + lb * 8, &As[c * 512]);
            g2lds16(Wb + (size_t)(gN + r) * HSZ + k0 + lb * 8, &Bs[c * 512]);
        }
        __syncthreads();
        #pragma unroll
        for (int kk = 0; kk < 2; ++kk) {
            short8 a[4], b[4];
            #pragma unroll
            for (int i = 0; i < 4; ++i) {
                int m = wm + i * 16 + l;
                a[i] = *(const short8*)&As[m * 64 + (((quad + kk * 4) ^ (m & 7)) << 3)];
                int n = wn + i * 16 + l;
                b[i] = *(const short8*)&Bs[n * 64 + (((quad + kk * 4) ^ (n & 7)) << 3)];
            }
            #pragma unroll
            for (int i = 0; i < 4; ++i)
                #pragma unroll
                for (int j = 0; j < 4; ++j)
                    acc[i][j] = __builtin_amdgcn_mfma_f32_16x16x32_bf16(
                        a[i], b[j], acc[i][j], 0, 0, 0);
        }
    }

    const int mat = gN >> 10;                   // 0=q 1=k 2=v

    if (mat == 2) {
        // V: bias + LDS transpose, write [bh][d][s] with permuted key blocks
        __syncthreads();
        #pragma unroll
        for (int j = 0; j < 4; ++j) {
            int fl = wn + j * 16 + l;               // feature local 0..127
            float bv_ = bv[(gN & 1023) + fl];
            #pragma unroll
            for (int i = 0; i < 4; ++i)
                #pragma unroll
                for (int r = 0; r < 4; ++r)
                    Sm[fl * 132 + wm + i * 16 + quad * 4 + r]
                        = f2bf(acc[i][j][r] + bv_);
        }
        __syncthreads();
        const int bb = gM >> 11, ss0 = gM & (SEQ - 1);
        #pragma unroll
        for (int it = 0; it < 16; ++it) {
            int f = (tid >> 5) + it * 8;
            int c = (tid & 31) * 4;
            short4_t val = *(const short4_t*)&Sm[f * 132 + c];
            int b = (c >> 2) & 15;                  // logical block-of-4
            int cp = (c & ~63) | ((((b & 8) | ((b & 3) << 1) | ((b >> 2) & 1))) << 2);
            int nft = (gN & 1023) + f;
            int head = nft >> 6, d = nft & 63;
            *(short4_t*)&vT[(((size_t)(bb * NHEAD + head)) * HDIM + d) * SEQ
                            + ss0 + cp] = val;
        }
        return;
    }

    const float* bias = (mat == 0) ? bq : bk;
    short* dst        = (mat == 0) ? qo : ko;
    const float qscale = (mat == 0) ? 0.125f * LOG2E : 1.0f;

    #pragma unroll
    for (int j = 0; j < 4; ++j) {
        int nft = (gN & 1023) + wn + j * 16 + l;   // feature 0..1023
        float bv_ = bias[nft];
        int head = nft >> 6, d = nft & 63;
        #pragma unroll
        for (int i = 0; i < 4; ++i) {
            #pragma unroll
            for (int r = 0; r < 4; ++r) {
                int gr = gM + wm + i * 16 + quad * 4 + r;    // C row = quad*4+reg
                int bb = gr >> 11, ss = gr & (SEQ - 1);
                float val = (acc[i][j][r] + bv_) * qscale;
                dst[((((size_t)bb * NHEAD + head) * SEQ + ss) << 6) + d] = f2bf(val);
            }
        }
    }
}

// ---------------------------------------------------------------------------
// K3: MFMA flash attention. Q-tile 128, grid 512, 512-THREAD BLOCKS (8 waves).
//   R5 showed occupancy is GRID-bound: 512 blocks x 4 waves = 2048 waves =
//   8 waves/CU ceiling regardless of LDS/registers. THIS ROUND: same Q-tile,
//   same staging totals/cadence, but 8 waves/block with each wave owning
//   16 queries x all 64 keys (16 = one MFMA N-tile, so per-MFMA efficiency
//   unchanged; query loop collapses to a singleton -> all swizzle and
//   V-permutation contracts are byte-identical). 512 blocks x 8 waves =
//   4096 waves = 16 waves/CU. Registers: o[4]=16 acc, aq[2]=8, s[4]=16
//   transient -> ~75 total; __launch_bounds__(512,4) caps at 128 (1.7x
//   headroom; FETCH_SIZE is the spill tripwire per R3). LDS 48KB.
//   Per block per tile: 8 waves x 16 MFMA = 128 MFMA (same as 4 x 32),
//   K/V staged once -> staging traffic, barriers, FETCH all unchanged.
// ---------------------------------------------------------------------------
__global__ __launch_bounds__(512, 4) void attn_kernel(
    const short* __restrict__ Qg, const short* __restrict__ Kg,
    const short* __restrict__ VTg, const float* __restrict__ maskw,
    float* __restrict__ out)
{
    __shared__ short Qs[128 * 64];                 // 16KB
    __shared__ alignas(16) short Ks[2][64 * 64];   // 16KB dbuf
    __shared__ alignas(16) short Vt[2][64 * 64];   // 16KB dbuf

    const int tid  = threadIdx.x;
    const int lane = tid & 63;
    const int w    = tid >> 6;              // 0..7
    const int l    = lane & 15, quad = lane >> 4;
    const int idx  = blockIdx.x;
    const int bh   = idx & 31;              // bh%8 == XCD -> K/V stays in one L2
    const int qt   = idx >> 5;              // 16 Q-tiles of 128
    const int batch = bh >> 4, head = bh & 15;
    const int ci = lane >> 3, pb = lane & 7;

    const short* Qb = Qg + ((size_t)bh * SEQ + qt * 128) * HDIM;
    const short* Kb = Kg + (size_t)bh * SEQ * HDIM;
    const short* Vb = VTg + (size_t)bh * HDIM * SEQ;
    const float* mrow = maskw + (size_t)batch * SEQ;   // pre-scaled by log2e

    // prologue: stage Q tile (16 chunks, 2/wave) + K/V tile 0 (1 K + 1 V /wave)
    #pragma unroll
    for (int u = 0; u < 2; ++u) {
        int c = w * 2 + u;
        int r = c * 8 + ci;
        int lb = pb ^ (r & 7);
        g2lds16(Qb + (size_t)r * HDIM + lb * 8, &Qs[c * 512]);
    }
    {
        int c = w;                           // chunk 0..7
        int r = c * 8 + ci;
        int lb = pb ^ (r & 7);
        g2lds16(Kb + (size_t)r * HDIM + lb * 8, &Ks[0][c * 512]);
        g2lds16(Vb + (size_t)r * SEQ + lb * 8, &Vt[0][c * 512]);
    }
    __syncthreads();

    // hoist Q B-fragments: this wave's 16 queries = w*16 + l
    short8 aq[2];
    #pragma unroll
    for (int kk = 0; kk < 2; ++kk) {
        int m = w * 16 + l;
        aq[kk] = *(const short8*)&Qs[m * 64 + (((quad + kk * 4) ^ (m & 7)) << 3)];
    }

    floatx4 o[4] = {};
    float l_i = 0.f;

    for (int kt = 0; kt < SEQ / 64; ++kt) {
        const int cur = kt & 1, nxt = cur ^ 1;
        if (kt + 1 < SEQ / 64) {            // prefetch next tile (overlaps compute)
            const int r0 = (kt + 1) * 64;
            int c = w;
            int r = c * 8 + ci;
            int lb = pb ^ (r & 7);
            g2lds16(Kb + (size_t)(r0 + r) * HDIM + lb * 8, &Ks[nxt][c * 512]);
            g2lds16(Vb + (size_t)r * SEQ + r0 + lb * 8, &Vt[nxt][c * 512]);
        }

        // S^T = K Q^T + mask; keys m*16 + quad*4 + r (all 64), queries w*16+l
        const float* mg = mrow + kt * 64;
        floatx4 s[4];
        #pragma unroll
        for (int m = 0; m < 4; ++m) {
            float4 mq = *(const float4*)&mg[m * 16 + quad * 4];
            floatx4 ini = {mq.x, mq.y, mq.z, mq.w};
            s[m] = ini;
        }
        #pragma unroll
        for (int kk = 0; kk < 2; ++kk) {
            short8 ak[4];
            #pragma unroll
            for (int m = 0; m < 4; ++m) {
                int kr = m * 16 + l;
                ak[m] = *(const short8*)&Ks[cur][kr * 64 + (((quad + kk * 4) ^ (kr & 7)) << 3)];
            }
            __builtin_amdgcn_s_setprio(1);
            #pragma unroll
            for (int m = 0; m < 4; ++m)
                s[m] = __builtin_amdgcn_mfma_f32_16x16x32_bf16(
                    ak[m], aq[kk], s[m], 0, 0, 0);
            __builtin_amdgcn_s_setprio(0);
        }

        // P = exp2(s); l partial per lane (cross-quad reduce deferred to end)
        {
            float rs = 0.f;
            #pragma unroll
            for (int m = 0; m < 4; ++m) {
                s[m][0] = ex2(s[m][0]);
                s[m][1] = ex2(s[m][1]);
                s[m][2] = ex2(s[m][2]);
                s[m][3] = ex2(s[m][3]);
                rs += (s[m][0] + s[m][1]) + (s[m][2] + s[m][3]);
            }
            l_i += rs;
        }

        // O += P V: two K=32 steps (kb = 32-key half; same contract as before)
        #pragma unroll
        for (int kb = 0; kb < 2; ++kb) {
            short8 bvf[4];
            #pragma unroll
            for (int nd = 0; nd < 4; ++nd) {
                int d = nd * 16 + l;
                bvf[nd] = *(const short8*)&Vt[cur][d * 64 + (((kb * 4 + quad) ^ (d & 7)) << 3)];
            }
            short8 ap;
            {
                union { unsigned u[4]; short8 s8; } pu;
                pu.u[0] = pk2(s[2 * kb][0], s[2 * kb][1]);
                pu.u[1] = pk2(s[2 * kb][2], s[2 * kb][3]);
                pu.u[2] = pk2(s[2 * kb + 1][0], s[2 * kb + 1][1]);
                pu.u[3] = pk2(s[2 * kb + 1][2], s[2 * kb + 1][3]);
                ap = pu.s8;
            }
            __builtin_amdgcn_s_setprio(1);
            #pragma unroll
            for (int nd = 0; nd < 4; ++nd)
                o[nd] = __builtin_amdgcn_mfma_f32_16x16x32_bf16(
                    ap, bvf[nd], o[nd], 0, 0, 0);
            __builtin_amdgcn_s_setprio(0);
        }

        __syncthreads();   // drains prefetch vmcnt + protects buffer swap
    }

    // ---- epilogue: each wave owns its 16 queries; no cross-wave combine ----
    {
        float t = l_i;
        t += __shfl_xor(t, 16);
        t += __shfl_xor(t, 32);
        l_i = t;
    }
    // out[b][s][h*64+d] fp32; query = w*16 + quad*4 + r, d = nd*16 + l
    #pragma unroll
    for (int r = 0; r < 4; ++r) {
        float inv = 1.0f / __shfl(l_i, (lane & 48) + quad * 4 + r);
        int qrow = qt * 128 + w * 16 + quad * 4 + r;
        #pragma unroll
        for (int nd = 0; nd < 4; ++nd)
            out[((size_t)batch * SEQ + qrow) * HSZ + head * HDIM + nd * 16 + l]
                = o[nd][r] * inv;
    }
}

extern "C" void kernel_launch(void* const* d_in, const int* in_sizes, int n_in,
                              void* d_out, int out_size, void* d_ws, size_t ws_size,
                              hipStream_t stream) {
    const float* hs   = (const float*)d_in[0];
    const float* mask = (const float*)d_in[1];
    const float* Wq   = (const float*)d_in[2];
    const float* bq   = (const float*)d_in[3];
    const float* Wk   = (const float*)d_in[4];
    const float* bk   = (const float*)d_in[5];
    const float* Wv   = (const float*)d_in[6];
    const float* bv   = (const float*)d_in[7];
    float* out = (float*)d_out;

    // workspace (shorts): Xb 4.19M | Wb 3.15M | qb | kb | vT 4.19M each | Mw
    short* Xb = (short*)d_ws;
    short* Wb = Xb + 4194304;
    short* qb = Wb + 3145728;
    short* kb = qb + 4194304;
    short* vT = kb + 4194304;
    float* Mw = (float*)(vT + 4194304);   // 4096 floats

    convert_kernel<<<7172, 256, 0, stream>>>(
        (const float4*)hs, (const float4*)Wq, (const float4*)Wk, (const float4*)Wv,
        (const float4*)mask, (short4_t*)Xb, (short4_t*)Wb, (float4*)Mw);

    dim3 g2(3 * HSZ / 128, BATCH * SEQ / 128);   // 24 x 32
    qkv_mfma_kernel<<<g2, 256, 0, stream>>>(Xb, Wb, bq, bk, bv, qb, kb, vT);

    attn_kernel<<<512, 512, 0, stream>>>(qb, kb, vT, Mw, out);
}

// Round 7
// 155.965 us; speedup vs baseline: 1.0290x; 1.0290x over previous
//
#include <hip/hip_runtime.h>
#include <hip/hip_bf16.h>
#include <math.h>

#define HSZ   1024
#define NHEAD 16
#define HDIM  64
#define BATCH 2
#define SEQ   2048

#define LOG2E 1.4426950408889634f

typedef __attribute__((ext_vector_type(8))) short short8;
typedef __attribute__((ext_vector_type(4))) short short4_t;
typedef __attribute__((ext_vector_type(4))) float floatx4;

typedef __attribute__((address_space(1))) const unsigned int gu32;
typedef __attribute__((address_space(3))) unsigned int lu32;

__device__ __forceinline__ void g2lds16(const void* g, void* l) {
    // async global->LDS DMA, 16B per lane; LDS dest = wave-uniform base + lane*16
    __builtin_amdgcn_global_load_lds((gu32*)g, (lu32*)l, 16, 0, 0);
}

__device__ __forceinline__ short f2bf(float f) {
    union { float f; unsigned u; } v; v.f = f;
    unsigned r = (v.u + 0x7FFF + ((v.u >> 16) & 1)) >> 16;  // RNE
    return (short)r;
}

__device__ __forceinline__ unsigned pk2(float a, float b) {
    __hip_bfloat162 h = __float22bfloat162_rn(make_float2(a, b));
    return *(unsigned*)&h;   // low = a, high = b
}

__device__ __forceinline__ float ex2(float x) {
#if __has_builtin(__builtin_amdgcn_exp2f)
    return __builtin_amdgcn_exp2f(x);
#else
    return exp2f(x);
#endif
}

// ---------------------------------------------------------------------------
// K1: fp32 -> bf16 convert (X, Wq|Wk|Wv concat) + mask prescale by log2e
// ---------------------------------------------------------------------------
__global__ __launch_bounds__(256) void convert_kernel(
    const float4* __restrict__ X, const float4* __restrict__ Wq,
    const float4* __restrict__ Wk, const float4* __restrict__ Wv,
    const float4* __restrict__ Mask,
    short4_t* __restrict__ Xb, short4_t* __restrict__ Wb,
    float4* __restrict__ Mw)
{
    int idx = blockIdx.x * 256 + threadIdx.x;      // 1,836,032 total
    if (idx >= 1835008) {                           // mask: 1024 float4
        int t = idx - 1835008;
        float4 f = Mask[t];
        float4 o;
        o.x = f.x * LOG2E; o.y = f.y * LOG2E;
        o.z = f.z * LOG2E; o.w = f.w * LOG2E;
        Mw[t] = o;
        return;
    }
    const float4* src; short4_t* dst;
    if (idx < 1048576) { src = X + idx; dst = Xb + idx; }
    else {
        int t = idx - 1048576;
        int sel = t >> 18;                          // 262144 float4 per W
        int wi  = t & 0x3FFFF;
        src = (sel == 0 ? Wq : sel == 1 ? Wk : Wv) + wi;
        dst = Wb + (sel << 18) + wi;
    }
    float4 f = *src;
    short4_t o;
    o.x = f2bf(f.x); o.y = f2bf(f.y); o.z = f2bf(f.z); o.w = f2bf(f.w);
    *dst = o;
}

// ---------------------------------------------------------------------------
// K2: QKV projection, bf16 MFMA. C[4096][3072] = Xb[4096][1024] * Wb^T.
// 128x128 tile, BK=64, global_load_lds w=16, XOR-swizzled LDS.
// q -> [B,NH,S,HD] scaled by 0.125*log2e; k -> [B,NH,S,HD];
// v -> TRANSPOSED [B*NH, HD, S] with key order PERMUTED within each
//     64-column group: block-of-4 b=(kh,jh,q) -> kh*8+q*2+jh, so the
//     attention PV A-fragment (packed from the S^T C-layout without any
//     cross-lane moves) contracts against matching V columns.
// ---------------------------------------------------------------------------
__global__ __launch_bounds__(256, 3) void qkv_mfma_kernel(
    const short* __restrict__ Xb, const short* __restrict__ Wb,
    const float* __restrict__ bq, const float* __restrict__ bk,
    const float* __restrict__ bv,
    short* __restrict__ qo, short* __restrict__ ko, short* __restrict__ vT)
{
    __shared__ short Sm[128 * 132];      // A/B staging (16384) + V transpose (16896)
    short* As = Sm;
    short* Bs = Sm + 8192;

    const int tid  = threadIdx.x;
    const int lane = tid & 63;
    const int w    = tid >> 6;
    const int l    = lane & 15, quad = lane >> 4;
    const int gM   = blockIdx.y * 128;
    const int gN   = blockIdx.x * 128;      // 0..3071 across q|k|v
    const int wm   = (w >> 1) * 64, wn = (w & 1) * 64;
    const int ci   = lane >> 3, pb = lane & 7;

    floatx4 acc[4][4] = {};

    for (int kt = 0; kt < HSZ / 64; ++kt) {
        const int k0 = kt * 64;
        __syncthreads();
        #pragma unroll
        for (int u = 0; u < 4; ++u) {
            int c  = w * 4 + u;                 // chunk 0..15 (1KB each)
            int r  = c * 8 + ci;                // tile row
            int lb = pb ^ (r & 7);              // logical 16B block
            g2lds16(Xb + (size_t)(gM + r) * HSZ + k0 + lb * 8, &As[c * 512]);
            g2lds16(Wb + (size_t)(gN + r) * HSZ + k0 + lb * 8, &Bs[c * 512]);
        }
        __syncthreads();
        #pragma unroll
        for (int kk = 0; kk < 2; ++kk) {
            short8 a[4], b[4];
            #pragma unroll
            for (int i = 0; i < 4; ++i) {
                int m = wm + i * 16 + l;
                a[i] = *(const short8*)&As[m * 64 + (((quad + kk * 4) ^ (m & 7)) << 3)];
                int n = wn + i * 16 + l;
                b[i] = *(const short8*)&Bs[n * 64 + (((quad + kk * 4) ^ (n & 7)) << 3)];
            }
            #pragma unroll
            for (int i = 0; i < 4; ++i)
                #pragma unroll
                for (int j = 0; j < 4; ++j)
                    acc[i][j] = __builtin_amdgcn_mfma_f32_16x16x32_bf16(
                        a[i], b[j], acc[i][j], 0, 0, 0);
        }
    }

    const int mat = gN >> 10;                   // 0=q 1=k 2=v

    if (mat == 2) {
        // V: bias + LDS transpose, write [bh][d][s] with permuted key blocks
        __syncthreads();
        #pragma unroll
        for (int j = 0; j < 4; ++j) {
            int fl = wn + j * 16 + l;               // feature local 0..127
            float bv_ = bv[(gN & 1023) + fl];
            #pragma unroll
            for (int i = 0; i < 4; ++i)
                #pragma unroll
                for (int r = 0; r < 4; ++r)
                    Sm[fl * 132 + wm + i * 16 + quad * 4 + r]
                        = f2bf(acc[i][j][r] + bv_);
        }
        __syncthreads();
        const int bb = gM >> 11, ss0 = gM & (SEQ - 1);
        #pragma unroll
        for (int it = 0; it < 16; ++it) {
            int f = (tid >> 5) + it * 8;
            int c = (tid & 31) * 4;
            short4_t val = *(const short4_t*)&Sm[f * 132 + c];
            int b = (c >> 2) & 15;                  // logical block-of-4
            int cp = (c & ~63) | ((((b & 8) | ((b & 3) << 1) | ((b >> 2) & 1))) << 2);
            int nft = (gN & 1023) + f;
            int head = nft >> 6, d = nft & 63;
            *(short4_t*)&vT[(((size_t)(bb * NHEAD + head)) * HDIM + d) * SEQ
                            + ss0 + cp] = val;
        }
        return;
    }

    const float* bias = (mat == 0) ? bq : bk;
    short* dst        = (mat == 0) ? qo : ko;
    const float qscale = (mat == 0) ? 0.125f * LOG2E : 1.0f;

    #pragma unroll
    for (int j = 0; j < 4; ++j) {
        int nft = (gN & 1023) + wn + j * 16 + l;   // feature 0..1023
        float bv_ = bias[nft];
        int head = nft >> 6, d = nft & 63;
        #pragma unroll
        for (int i = 0; i < 4; ++i) {
            #pragma unroll
            for (int r = 0; r < 4; ++r) {
                int gr = gM + wm + i * 16 + quad * 4 + r;    // C row = quad*4+reg
                int bb = gr >> 11, ss = gr & (SEQ - 1);
                float val = (acc[i][j][r] + bv_) * qscale;
                dst[((((size_t)bb * NHEAD + head) * SEQ + ss) << 6) + d] = f2bf(val);
            }
        }
    }
}

// ---------------------------------------------------------------------------
// K3: MFMA flash attention, DE-PHASED. Q-tile 128, 512-thread blocks, grid 512.
//   R6 proved the plateau isn't occupancy (2x waves, same 53us): all waves
//   sit in the SAME phase (barrier lockstep) so pipes are used in aligned
//   bursts (MfmaUtil 27 / VALUBusy 47, neither saturated). THIS ROUND:
//   (1) T15 S-pipeline: per phase compute QK^T(t+1) [indep MFMA] BEFORE
//       softmax+PV(t) [indep VALU/trans] - mixed streams per wave so the
//       4 waves/SIMD can overlap pipes even in lockstep.
//   (2) mask row staged ONCE in LDS (8KB) - kills the per-tile global-load
//       chain head and keeps vmcnt pure-DMA.
//   (3) counted vmcnt: K prefetch distance 3, V distance 2, triple buffers
//       via rotating pointers; per-phase "s_waitcnt vmcnt(2)" + raw
//       s_barrier keeps this phase's 2 DMAs in flight across the barrier
//       (phase u+1 only needs loads issued at u-1; R2's flaw removed).
//   LDS 72KB -> 2 blocks/CU; invariant: at phase u, kR=K(u+1), vR=V(u).
// ---------------------------------------------------------------------------
__global__ __launch_bounds__(512, 4) void attn_kernel(
    const short* __restrict__ Qg, const short* __restrict__ Kg,
    const short* __restrict__ VTg, const float* __restrict__ maskw,
    float* __restrict__ out)
{
    __shared__ short Qs[128 * 64];                  // 16KB
    __shared__ alignas(16) short Kb3[3][64 * 64];   // 24KB triple buffer
    __shared__ alignas(16) short Vb3[3][64 * 64];   // 24KB triple buffer
    __shared__ alignas(16) float Mf[SEQ];           // 8KB pre-scaled mask row

    const int tid  = threadIdx.x;
    const int lane = tid & 63;
    const int w    = tid >> 6;              // 0..7
    const int l    = lane & 15, quad = lane >> 4;
    const int idx  = blockIdx.x;
    const int bh   = idx & 31;              // bh%8 == XCD -> K/V stays in one L2
    const int qt   = idx >> 5;              // 16 Q-tiles of 128
    const int batch = bh >> 4, head = bh & 15;
    const int ci = lane >> 3, pb = lane & 7;

    const short* Qb = Qg + ((size_t)bh * SEQ + qt * 128) * HDIM;
    const short* Kg_ = Kg + (size_t)bh * SEQ * HDIM;
    const short* Vg_ = VTg + (size_t)bh * HDIM * SEQ;
    const float* mrow = maskw + (size_t)batch * SEQ;   // pre-scaled by log2e

    // ---- prologue staging: Q (2 chunks/wave), mask row (1/wave),
    //      K0,K1,K2 and V0,V1 (1 chunk/wave each) ----
    #pragma unroll
    for (int u = 0; u < 2; ++u) {
        int c = w * 2 + u;
        int r = c * 8 + ci;
        int lb = pb ^ (r & 7);
        g2lds16(Qb + (size_t)r * HDIM + lb * 8, &Qs[c * 512]);
    }
    g2lds16(mrow + w * 256 + lane * 4, &Mf[w * 256]);
    {
        int r = w * 8 + ci;
        int lb = pb ^ (r & 7);
        g2lds16(Kg_ + (size_t)r * HDIM + lb * 8,          &Kb3[0][w * 512]);
        g2lds16(Kg_ + (size_t)(64 + r) * HDIM + lb * 8,   &Kb3[1][w * 512]);
        g2lds16(Kg_ + (size_t)(128 + r) * HDIM + lb * 8,  &Kb3[2][w * 512]);
        g2lds16(Vg_ + (size_t)r * SEQ + lb * 8,           &Vb3[0][w * 512]);
        g2lds16(Vg_ + (size_t)r * SEQ + 64 + lb * 8,      &Vb3[1][w * 512]);
    }
    __syncthreads();

    // hoist Q B-fragments: this wave's 16 queries = w*16 + l
    short8 aq[2];
    #pragma unroll
    for (int kk = 0; kk < 2; ++kk) {
        int m = w * 16 + l;
        aq[kk] = *(const short8*)&Qs[m * 64 + (((quad + kk * 4) ^ (m & 7)) << 3)];
    }

    floatx4 o[4] = {};
    float l_i = 0.f;
    floatx4 sA[4], sB[4];

    // rotating LDS buffer pointers (wave-uniform)
    const short* kR; const short* kP; short* kW;
    const short* vR; const short* vP; short* vW;

    auto DMAK = [&](int t) {                // stage K(t) -> kW
        int r = w * 8 + ci;
        int lb = pb ^ (r & 7);
        g2lds16(Kg_ + (size_t)(t * 64 + r) * HDIM + lb * 8, kW + w * 512);
    };
    auto DMAV = [&](int t) {                // stage V(t) -> vW
        int r = w * 8 + ci;
        int lb = pb ^ (r & 7);
        g2lds16(Vg_ + (size_t)r * SEQ + t * 64 + lb * 8, vW + w * 512);
    };
    auto ROT = [&]() {
        const short* tk = kR; kR = kP; kP = kW; kW = (short*)tk;
        const short* tv = vR; vR = vP; vP = vW; vW = (short*)tv;
    };

    // QK^T for tile u1 into s (S^T = K Q^T + mask); keys m*16+quad*4+r
    auto QKT = [&](floatx4 (&s)[4], const short* kbuf, int u1) {
        const float* mg = &Mf[u1 * 64];
        #pragma unroll
        for (int m = 0; m < 4; ++m) {
            float4 mq = *(const float4*)&mg[m * 16 + quad * 4];
            floatx4 ini = {mq.x, mq.y, mq.z, mq.w};
            s[m] = ini;
        }
        #pragma unroll
        for (int kk = 0; kk < 2; ++kk) {
            short8 ak[4];
            #pragma unroll
            for (int m = 0; m < 4; ++m) {
                int kr = m * 16 + l;
                ak[m] = *(const short8*)&kbuf[kr * 64 + (((quad + kk * 4) ^ (kr & 7)) << 3)];
            }
            __builtin_amdgcn_s_setprio(1);
            #pragma unroll
            for (int m = 0; m < 4; ++m)
                s[m] = __builtin_amdgcn_mfma_f32_16x16x32_bf16(
                    ak[m], aq[kk], s[m], 0, 0, 0);
            __builtin_amdgcn_s_setprio(0);
        }
    };

    // softmax + PV for the tile held in s, V from vbuf
    auto SMPV = [&](floatx4 (&s)[4], const short* vbuf) {
        {
            float rs = 0.f;
            #pragma unroll
            for (int m = 0; m < 4; ++m) {
                s[m][0] = ex2(s[m][0]);
                s[m][1] = ex2(s[m][1]);
                s[m][2] = ex2(s[m][2]);
                s[m][3] = ex2(s[m][3]);
                rs += (s[m][0] + s[m][1]) + (s[m][2] + s[m][3]);
            }
            l_i += rs;
        }
        #pragma unroll
        for (int kb = 0; kb < 2; ++kb) {
            short8 bvf[4];
            #pragma unroll
            for (int nd = 0; nd < 4; ++nd) {
                int d = nd * 16 + l;
                bvf[nd] = *(const short8*)&vbuf[d * 64 + (((kb * 4 + quad) ^ (d & 7)) << 3)];
            }
            short8 ap;
            {
                union { unsigned u[4]; short8 s8; } pu;
                pu.u[0] = pk2(s[2 * kb][0], s[2 * kb][1]);
                pu.u[1] = pk2(s[2 * kb][2], s[2 * kb][3]);
                pu.u[2] = pk2(s[2 * kb + 1][0], s[2 * kb + 1][1]);
                pu.u[3] = pk2(s[2 * kb + 1][2], s[2 * kb + 1][3]);
                ap = pu.s8;
            }
            __builtin_amdgcn_s_setprio(1);
            #pragma unroll
            for (int nd = 0; nd < 4; ++nd)
                o[nd] = __builtin_amdgcn_mfma_f32_16x16x32_bf16(
                    ap, bvf[nd], o[nd], 0, 0, 0);
            __builtin_amdgcn_s_setprio(0);
        }
    };

    // S(0) from Kb3[0]; then barrier so Kb3[0] can be rewritten by prefetch.
    QKT(sA, &Kb3[0][0], 0);
    __syncthreads();
    kR = &Kb3[1][0]; kP = &Kb3[2][0]; kW = &Kb3[0][0];
    vR = &Vb3[0][0]; vP = &Vb3[1][0]; vW = &Vb3[2][0];

#define PHASE_BAR(N)                                        \
    asm volatile("s_waitcnt vmcnt(" #N ")" ::: "memory");   \
    __builtin_amdgcn_s_barrier();                           \
    asm volatile("" ::: "memory");

    // main loop: phases u = 0..27 (all prefetch guards true, vmcnt(2))
    for (int t = 0; t < 28; t += 2) {
        // phase A (tile t): sA ready; compute S(t+1) into sB
        DMAK(t + 3); DMAV(t + 2);
        QKT(sB, kR, t + 1);
        SMPV(sA, vR);
        PHASE_BAR(2)
        ROT();
        // phase B (tile t+1)
        DMAK(t + 4); DMAV(t + 3);
        QKT(sA, kR, t + 2);
        SMPV(sB, vR);
        PHASE_BAR(2)
        ROT();
    }
    // u=28: prefetch K31,V30
    DMAK(31); DMAV(30);
    QKT(sB, kR, 29);
    SMPV(sA, vR);
    PHASE_BAR(2)
    ROT();
    // u=29: prefetch V31 only
    DMAV(31);
    QKT(sA, kR, 30);
    SMPV(sB, vR);
    PHASE_BAR(1)
    ROT();
    // u=30: no prefetch
    QKT(sB, kR, 31);
    SMPV(sA, vR);
    PHASE_BAR(0)
    ROT();
    // u=31: final tile
    SMPV(sB, vR);
#undef PHASE_BAR

    // ---- epilogue: each wave owns its 16 queries; no cross-wave combine ----
    {
        float t = l_i;
        t += __shfl_xor(t, 16);
        t += __shfl_xor(t, 32);
        l_i = t;
    }
    // out[b][s][h*64+d] fp32; query = w*16 + quad*4 + r, d = nd*16 + l
    #pragma unroll
    for (int r = 0; r < 4; ++r) {
        float inv = 1.0f / __shfl(l_i, (lane & 48) + quad * 4 + r);
        int qrow = qt * 128 + w * 16 + quad * 4 + r;
        #pragma unroll
        for (int nd = 0; nd < 4; ++nd)
            out[((size_t)batch * SEQ + qrow) * HSZ + head * HDIM + nd * 16 + l]
                = o[nd][r] * inv;
    }
}

extern "C" void kernel_launch(void* const* d_in, const int* in_sizes, int n_in,
                              void* d_out, int out_size, void* d_ws, size_t ws_size,
                              hipStream_t stream) {
    const float* hs   = (const float*)d_in[0];
    const float* mask = (const float*)d_in[1];
    const float* Wq   = (const float*)d_in[2];
    const float* bq   = (const float*)d_in[3];
    const float* Wk   = (const float*)d_in[4];
    const float* bk   = (const float*)d_in[5];
    const float* Wv   = (const float*)d_in[6];
    const float* bv   = (const float*)d_in[7];
    float* out = (float*)d_out;

    // workspace (shorts): Xb 4.19M | Wb 3.15M | qb | kb | vT 4.19M each | Mw
    short* Xb = (short*)d_ws;
    short* Wb = Xb + 4194304;
    short* qb = Wb + 3145728;
    short* kb = qb + 4194304;
    short* vT = kb + 4194304;
    float* Mw = (float*)(vT + 4194304);   // 4096 floats

    convert_kernel<<<7172, 256, 0, stream>>>(
        (const float4*)hs, (const float4*)Wq, (const float4*)Wk, (const float4*)Wv,
        (const float4*)mask, (short4_t*)Xb, (short4_t*)Wb, (float4*)Mw);

    dim3 g2(3 * HSZ / 128, BATCH * SEQ / 128);   // 24 x 32
    qkv_mfma_kernel<<<g2, 256, 0, stream>>>(Xb, Wb, bq, bk, bv, qb, kb, vT);

    attn_kernel<<<512, 512, 0, stream>>>(qb, kb, vT, Mw, out);
}